// Round 5
// baseline (1115.863 us; speedup 1.0000x reference)
//
#include <hip/hip_runtime.h>
#include <math.h>

#define BQ 4
#define SQ 2048
#define DQ 512
#define YQ 8922
#define TQ 32
#define EQ 100
#define EP 128      // E padded for MFMA K-steps
#define KQ 9
#define LD 128      // LDS leading dim (bf16 elems) = 256B rows, XOR-swizzled
#define YPAD 8960   // U rows padded to multiple of 128

typedef float f32x4 __attribute__((ext_vector_type(4)));
typedef short s16x8 __attribute__((ext_vector_type(8)));

static __device__ __forceinline__ f32x4 mfma16(s16x8 a, s16x8 b, f32x4 c) {
  return __builtin_amdgcn_mfma_f32_16x16x32_bf16(a, b, c, 0, 0, 0);
}

static __device__ __forceinline__ ushort f2bf(float f) {
  union { float f; unsigned u; } v; v.f = f;
  unsigned r = (v.u + 0x7FFFu + ((v.u >> 16) & 1u)) >> 16;
  return (ushort)r;
}

// unaligned (4B) 16-byte load
static __device__ __forceinline__ f32x4 ld4u(const float* p) {
  f32x4 v; __builtin_memcpy(&v, p, 16); return v;
}

// T2 swizzle, full 4-bit: 16B-chunk index XOR'd with row&15.
// (R2->R3: &7 left 4-way aliasing, 3.15e8 conflicts; &15 fixed it: 1.1e7.)
static __device__ __forceinline__ int swz_chunk(int row, int chunk) {
  return chunk ^ (row & 15);
}

// ---------------- prep: x -> bf16 [B][S][D] and transposed bf16 [B][D][S] ----
__global__ void k_prep_x(const float* __restrict__ x, ushort* __restrict__ xb,
                         ushort* __restrict__ xT) {
  __shared__ ushort sm[32][33];
  int b = blockIdx.z;
  int s0 = blockIdx.x * 32;
  int d0 = blockIdx.y * 32;
  int tx = threadIdx.x, ty = threadIdx.y;
  float v = x[((size_t)b * SQ + s0 + ty) * DQ + d0 + tx];
  ushort h = f2bf(v);
  xb[((size_t)b * SQ + s0 + ty) * DQ + d0 + tx] = h;
  sm[ty][tx] = h;
  __syncthreads();
  xT[((size_t)b * DQ + d0 + ty) * SQ + s0 + tx] = sm[tx][ty];
}

// ---------------- pack conv_w [D][E][K] -> Wp bf16 [K][D][EP] (e>=100 -> 0) --
__global__ void k_pack_w(const float* __restrict__ cw, ushort* __restrict__ Wp) {
  int i = blockIdx.x * 256 + threadIdx.x;
  if (i >= KQ * DQ * EP) return;
  int e = i & (EP - 1);
  int d = (i >> 7) & (DQ - 1);
  int kk = i >> 16;
  float v = (e < EQ) ? cw[((size_t)d * EQ + e) * KQ + kk] : 0.f;
  Wp[i] = f2bf(v);
}

// ---------------- conv + maxpool + tanh + scale -> U bf16 [YQ][D] -----------
__launch_bounds__(256, 2)
__global__ void k_conv(const int* __restrict__ c2t, const float* __restrict__ embed,
                       const ushort* __restrict__ Wp, const float* __restrict__ cb,
                       ushort* __restrict__ U) {
  __shared__ ushort sA[4 * TQ * LD];   // 32 KB: 4 labels x 32 t x 128 e
  __shared__ ushort sB[128 * LD];      // 32 KB: 128 d x 128 e (one kk)
  const f32x4 fz4 = {0.f, 0.f, 0.f, 0.f};
  const s16x8 sz8 = {0, 0, 0, 0, 0, 0, 0, 0};
  int tid = threadIdx.x;
  int d0 = blockIdx.x * 128;
  int y0 = blockIdx.y * 4;
  int lane = tid & 63, wave = tid >> 6;
  int wm = wave & 1, wn = wave >> 1;
  int lr = lane & 15, lg = lane >> 4;

  // stage all title embeddings for 4 labels: [4*32] rows x [LD] bf16, swizzled
  {
    int row = tid >> 1;
    int half = tid & 1;
    int yl = row >> 5, t = row & 31;
    int y = y0 + yl;
    const float* src = 0;
    if (y < YQ) src = embed + (size_t)c2t[y * TQ + t] * EQ + half * 64;
    #pragma unroll
    for (int j = 0; j < 16; ++j) {
      int col = half * 64 + j * 4;
      f32x4 v = fz4;
      if (src != 0 && col + 4 <= EQ) v = *(const f32x4*)(src + j * 4);
      ushort4 h = make_ushort4(f2bf(v.x), f2bf(v.y), f2bf(v.z), f2bf(v.w));
      int pc = swz_chunk(row, col >> 3);
      *(ushort4*)&sA[row * LD + pc * 8 + (col & 7)] = h;
    }
  }

  // B prologue: kk=0 via registers (same path as the steady-state prefetch)
  s16x8 breg[8];
  {
    const ushort* src = Wp + (size_t)d0 * EP;
    #pragma unroll
    for (int it = 0; it < 8; ++it) {
      int gi = tid + it * 256, r = gi >> 4, g = gi & 15;
      breg[it] = *(const s16x8*)(src + (size_t)r * EP + g * 8);
    }
    #pragma unroll
    for (int it = 0; it < 8; ++it) {
      int gi = tid + it * 256, r = gi >> 4, g = gi & 15;
      *(s16x8*)&sB[r * LD + swz_chunk(r, g) * 8] = breg[it];
    }
  }
  __syncthreads();

  f32x4 acc[4][4];
  #pragma unroll
  for (int i = 0; i < 4; ++i)
    #pragma unroll
    for (int j = 0; j < 4; ++j) acc[i][j] = fz4;

  for (int kk = 0; kk < KQ; ++kk) {
    // T14: issue next-kk weight loads into regs BEFORE compute
    if (kk + 1 < KQ) {
      const ushort* src = Wp + ((size_t)(kk + 1) * DQ + d0) * EP;
      #pragma unroll
      for (int it = 0; it < 8; ++it) {
        int gi = tid + it * 256, r = gi >> 4, g = gi & 15;
        breg[it] = *(const s16x8*)(src + (size_t)r * EP + g * 8);
      }
    }
    #pragma unroll
    for (int ee = 0; ee < 4; ++ee) {
      s16x8 af[4], bfr[4];
      #pragma unroll
      for (int i = 0; i < 4; ++i) {
        int rowm = wm * 64 + i * 16 + lr;
        int yl = rowm >> 5;
        int ts = (rowm & 31) + kk - 4;   // shifted time index
        s16x8 a = sz8;
        if ((unsigned)ts < (unsigned)TQ) {
          int row = yl * TQ + ts;
          a = *(const s16x8*)&sA[row * LD + swz_chunk(row, ee * 4 + lg) * 8];
        }
        af[i] = a;
      }
      #pragma unroll
      for (int i = 0; i < 4; ++i) {
        int row = wn * 64 + i * 16 + lr;
        bfr[i] = *(const s16x8*)&sB[row * LD + swz_chunk(row, ee * 4 + lg) * 8];
      }
      #pragma unroll
      for (int i = 0; i < 4; ++i)
        #pragma unroll
        for (int j = 0; j < 4; ++j)
          acc[i][j] = mfma16(af[i], bfr[j], acc[i][j]);
    }
    __syncthreads();           // all waves done reading sB for this kk
    if (kk + 1 < KQ) {
      #pragma unroll
      for (int it = 0; it < 8; ++it) {
        int gi = tid + it * 256, r = gi >> 4, g = gi & 15;
        *(s16x8*)&sB[r * LD + swz_chunk(r, g) * 8] = breg[it];
      }
      __syncthreads();         // sB(kk+1) visible
    }
  }

  // in-register epilogue: maxpool over t via in-lane fmax + shfl, tanh, scale
  const float scl = 0.04419417382415922f;   // 1/sqrt(D)
  #pragma unroll
  for (int L2 = 0; L2 < 2; ++L2) {
    int y = y0 + wm * 2 + L2;
    #pragma unroll
    for (int j = 0; j < 4; ++j) {
      float mx = -3.0e38f;
      #pragma unroll
      for (int ii = 0; ii < 2; ++ii)
        #pragma unroll
        for (int q = 0; q < 4; ++q)
          mx = fmaxf(mx, acc[L2 * 2 + ii][j][q]);
      mx = fmaxf(mx, __shfl_xor(mx, 16));
      mx = fmaxf(mx, __shfl_xor(mx, 32));
      if (lane < 16 && y < YQ) {
        int col = d0 + wn * 64 + j * 16 + lane;
        U[(size_t)y * DQ + col] = f2bf(tanhf(mx + cb[col]) * scl);
      }
    }
  }
}

// ---- scores = U . xb^T -> raw S (to sc) + per-(row,64col) {max,sumexp} -----
__launch_bounds__(256, 2)
__global__ void k_scores(const ushort* __restrict__ U, const ushort* __restrict__ xb,
                         float* __restrict__ sc, float* __restrict__ part) {
  __shared__ ushort sA[128 * LD];
  __shared__ ushort sB[128 * LD];
  const f32x4 fz4 = {0.f, 0.f, 0.f, 0.f};
  int tid = threadIdx.x;
  int s0 = blockIdx.x * 128;
  int y0 = blockIdx.y * 128;
  int b = blockIdx.z;
  const ushort* Ap = U + (size_t)y0 * DQ;
  const ushort* Bp = xb + ((size_t)b * SQ + s0) * DQ;
  f32x4 acc[4][4];
  #pragma unroll
  for (int i = 0; i < 4; ++i)
    #pragma unroll
    for (int j = 0; j < 4; ++j) acc[i][j] = fz4;
  int lane = tid & 63, wave = tid >> 6;
  int wm = wave & 1, wn = wave >> 1;
  int lr = lane & 15, lg = lane >> 4;

  for (int kc = 0; kc < DQ; kc += 128) {
    __syncthreads();
    #pragma unroll
    for (int it = 0; it < 8; ++it) {
      int gi = tid + it * 256;
      int r = gi >> 4, g = gi & 15;
      int pofs = r * LD + swz_chunk(r, g) * 8;
      *(s16x8*)&sA[pofs] = *(const s16x8*)(Ap + (size_t)r * DQ + kc + g * 8);
      *(s16x8*)&sB[pofs] = *(const s16x8*)(Bp + (size_t)r * DQ + kc + g * 8);
    }
    __syncthreads();
    #pragma unroll
    for (int ks = 0; ks < 4; ++ks) {
      s16x8 af[4], bfr[4];
      #pragma unroll
      for (int i = 0; i < 4; ++i) {
        int row = wm * 64 + i * 16 + lr;
        af[i] = *(const s16x8*)&sA[row * LD + swz_chunk(row, ks * 4 + lg) * 8];
      }
      #pragma unroll
      for (int i = 0; i < 4; ++i) {
        int row = wn * 64 + i * 16 + lr;
        bfr[i] = *(const s16x8*)&sB[row * LD + swz_chunk(row, ks * 4 + lg) * 8];
      }
      #pragma unroll
      for (int i = 0; i < 4; ++i)
        #pragma unroll
        for (int j = 0; j < 4; ++j)
          acc[i][j] = mfma16(af[i], bfr[j], acc[i][j]);
    }
  }
  float* out = sc + (size_t)b * YQ * SQ;
  int rb = wm * 64 + lg * 4;
  int cb_ = wn * 64 + lr;
  #pragma unroll
  for (int i = 0; i < 4; ++i)
    #pragma unroll
    for (int j = 0; j < 4; ++j) {
      int col = s0 + cb_ + j * 16;
      #pragma unroll
      for (int q = 0; q < 4; ++q) {
        int r = y0 + rb + i * 16 + q;
        if (r < YQ) out[(size_t)r * SQ + col] = acc[i][j][q];
      }
    }

  // softmax partials: per wave-row, max + sumexp over this wave's 64 cols.
  // lanes lg*16+lr: reduce over lr (contiguous 16) via shfl_xor 1..8.
  int hb = blockIdx.x * 2 + wn;   // 64-col block index in [0,32)
  #pragma unroll
  for (int i = 0; i < 4; ++i)
    #pragma unroll
    for (int q = 0; q < 4; ++q) {
      float mx = fmaxf(fmaxf(acc[i][0][q], acc[i][1][q]),
                       fmaxf(acc[i][2][q], acc[i][3][q]));
      #pragma unroll
      for (int o = 1; o < 16; o <<= 1) mx = fmaxf(mx, __shfl_xor(mx, o));
      float se = 0.f;
      #pragma unroll
      for (int j = 0; j < 4; ++j) se += __expf(acc[i][j][q] - mx);
      #pragma unroll
      for (int o = 1; o < 16; o <<= 1) se += __shfl_xor(se, o);
      int r = y0 + rb + i * 16 + q;
      if (lr == 0 && r < YQ) {
        float* pp = part + ((size_t)(b * YQ + r) * 32 + hb) * 2;
        pp[0] = mx;
        pp[1] = se;
      }
    }
}

// ---- merge 32 per-row partials -> rowstats {M, 1/Z} ------------------------
__global__ void k_smfix(const float* __restrict__ part, float* __restrict__ rs) {
  int t = blockIdx.x * 256 + threadIdx.x;
  if (t >= BQ * YQ) return;
  const float* pp = part + (size_t)t * 64;
  float M = -3.0e38f;
  #pragma unroll
  for (int h = 0; h < 32; ++h) M = fmaxf(M, pp[h * 2]);
  float Z = 0.f;
  #pragma unroll
  for (int h = 0; h < 32; ++h) Z += __expf(pp[h * 2] - M) * pp[h * 2 + 1];
  rs[t * 2] = M;
  rs[t * 2 + 1] = 1.0f / Z;
}

// ---- MODE B: in-place S -> alpha (f32) + optional bf16 copy ----------------
__global__ void k_alpha(float* __restrict__ a, const float* __restrict__ rs,
                        ushort* __restrict__ abf) {
  int r = blockIdx.x;              // b*YQ + y
  float M = rs[r * 2], iZ = rs[r * 2 + 1];
  float* p = a + (size_t)r * SQ;
  ushort* q = abf ? abf + (size_t)r * SQ : 0;
  int tid = threadIdx.x;
  #pragma unroll
  for (int i = 0; i < 8; ++i) {
    int e = tid + i * 256;
    float v = __expf(p[e] - M) * iZ;
    p[e] = v;
    if (q) q[e] = f2bf(v);
  }
}

// ---- MODE A pv: m = softmax(S) . x, fused exp + alpha write ----------------
// Reads raw S (f32, ws), stages p=exp(S-M) as bf16; designated s-chunks write
// alpha = p*iZ to d_out; epilogue scales m rows by iZ.
__launch_bounds__(256, 2)
__global__ void k_pv_f(const float* __restrict__ Sws, const float* __restrict__ rs,
                       const ushort* __restrict__ xT, float* __restrict__ mo,
                       float* __restrict__ aout) {
  __shared__ ushort sA[128 * LD];
  __shared__ ushort sB[128 * LD];
  const f32x4 fz4 = {0.f, 0.f, 0.f, 0.f};
  int tid = threadIdx.x;
  int d0 = blockIdx.x * 128;
  int y0 = blockIdx.y * 128;
  int b = blockIdx.z;
  const ushort* Bp = xT + ((size_t)b * DQ + d0) * SQ;
  f32x4 acc[4][4];
  #pragma unroll
  for (int i = 0; i < 4; ++i)
    #pragma unroll
    for (int j = 0; j < 4; ++j) acc[i][j] = fz4;
  int lane = tid & 63, wave = tid >> 6;
  int wm = wave & 1, wn = wave >> 1;
  int lr = lane & 15, lg = lane >> 4;

  for (int kc = 0; kc < SQ; kc += 128) {
    bool wr = (((kc >> 7) & 3) == (int)blockIdx.x);   // this block writes alpha chunk
    __syncthreads();
    #pragma unroll
    for (int it = 0; it < 8; ++it) {
      int gi = tid + it * 256;
      int r = gi >> 4, g = gi & 15;
      int y = y0 + r;
      int pofs = r * LD + swz_chunk(r, g) * 8;
      ushort h[8];
      if (y < YQ) {
        size_t base = ((size_t)b * YQ + y) * SQ + kc + g * 8;
        float M = rs[(b * YQ + y) * 2];
        float iZ = rs[(b * YQ + y) * 2 + 1];
        f32x4 v0 = *(const f32x4*)(Sws + base);
        f32x4 v1 = *(const f32x4*)(Sws + base + 4);
        float pe[8];
        #pragma unroll
        for (int k = 0; k < 4; ++k) pe[k] = __expf(v0[k] - M);
        #pragma unroll
        for (int k = 0; k < 4; ++k) pe[4 + k] = __expf(v1[k] - M);
        #pragma unroll
        for (int k = 0; k < 8; ++k) h[k] = f2bf(pe[k]);
        if (wr) {
          float* ao = aout + base;
          #pragma unroll
          for (int k = 0; k < 8; ++k) ao[k] = pe[k] * iZ;
        }
      } else {
        #pragma unroll
        for (int k = 0; k < 8; ++k) h[k] = 0;
      }
      #pragma unroll
      for (int k = 0; k < 8; ++k) sA[pofs + k] = h[k];
      *(s16x8*)&sB[pofs] = *(const s16x8*)(Bp + (size_t)r * SQ + kc + g * 8);
    }
    __syncthreads();
    #pragma unroll
    for (int ks = 0; ks < 4; ++ks) {
      s16x8 af[4], bfr[4];
      #pragma unroll
      for (int i = 0; i < 4; ++i) {
        int row = wm * 64 + i * 16 + lr;
        af[i] = *(const s16x8*)&sA[row * LD + swz_chunk(row, ks * 4 + lg) * 8];
      }
      #pragma unroll
      for (int i = 0; i < 4; ++i) {
        int row = wn * 64 + i * 16 + lr;
        bfr[i] = *(const s16x8*)&sB[row * LD + swz_chunk(row, ks * 4 + lg) * 8];
      }
      #pragma unroll
      for (int i = 0; i < 4; ++i)
        #pragma unroll
        for (int j = 0; j < 4; ++j)
          acc[i][j] = mfma16(af[i], bfr[j], acc[i][j]);
    }
  }
  float* out = mo + (size_t)b * YQ * DQ;
  int rb = wm * 64 + lg * 4;
  int cb_ = wn * 64 + lr;
  #pragma unroll
  for (int i = 0; i < 4; ++i)
    #pragma unroll
    for (int q = 0; q < 4; ++q) {
      int r = y0 + rb + i * 16 + q;
      if (r >= YQ) continue;
      float iZ = rs[(b * YQ + r) * 2 + 1];
      #pragma unroll
      for (int j = 0; j < 4; ++j) {
        int col = d0 + cb_ + j * 16;
        out[(size_t)r * DQ + col] = acc[i][j][q] * iZ;
      }
    }
}

// ---- MODE B pv: m = alpha . x (alpha already normalized) -------------------
template <bool BF16A>
__launch_bounds__(256, 2)
__global__ void k_pv(const float* __restrict__ alpha, const ushort* __restrict__ abf,
                     const ushort* __restrict__ xT, float* __restrict__ mo) {
  __shared__ ushort sA[128 * LD];
  __shared__ ushort sB[128 * LD];
  const f32x4 fz4 = {0.f, 0.f, 0.f, 0.f};
  int tid = threadIdx.x;
  int d0 = blockIdx.x * 128;
  int y0 = blockIdx.y * 128;
  int b = blockIdx.z;
  const float* Ap = alpha + ((size_t)b * YQ + y0) * SQ;
  const ushort* Af = abf + ((size_t)b * YQ + y0) * SQ;
  const ushort* Bp = xT + ((size_t)b * DQ + d0) * SQ;
  f32x4 acc[4][4];
  #pragma unroll
  for (int i = 0; i < 4; ++i)
    #pragma unroll
    for (int j = 0; j < 4; ++j) acc[i][j] = fz4;
  int lane = tid & 63, wave = tid >> 6;
  int wm = wave & 1, wn = wave >> 1;
  int lr = lane & 15, lg = lane >> 4;

  for (int kc = 0; kc < SQ; kc += 128) {
    __syncthreads();
    #pragma unroll
    for (int it = 0; it < 8; ++it) {
      int gi = tid + it * 256;
      int r = gi >> 4, g = gi & 15;
      int y = y0 + r;
      int pofs = r * LD + swz_chunk(r, g) * 8;
      if (BF16A) {
        s16x8 a = {0, 0, 0, 0, 0, 0, 0, 0};
        if (y < YQ) a = *(const s16x8*)(Af + (size_t)r * SQ + kc + g * 8);
        *(s16x8*)&sA[pofs] = a;
      } else {
        ushort4 h0 = make_ushort4(0, 0, 0, 0), h1 = make_ushort4(0, 0, 0, 0);
        if (y < YQ) {
          f32x4 v0 = ld4u(Ap + (size_t)r * SQ + kc + g * 8);
          f32x4 v1 = ld4u(Ap + (size_t)r * SQ + kc + g * 8 + 4);
          h0 = make_ushort4(f2bf(v0.x), f2bf(v0.y), f2bf(v0.z), f2bf(v0.w));
          h1 = make_ushort4(f2bf(v1.x), f2bf(v1.y), f2bf(v1.z), f2bf(v1.w));
        }
        *(ushort4*)&sA[pofs] = h0;
        *(ushort4*)&sA[pofs + 4] = h1;
      }
      *(s16x8*)&sB[pofs] = *(const s16x8*)(Bp + (size_t)r * SQ + kc + g * 8);
    }
    __syncthreads();
    #pragma unroll
    for (int ks = 0; ks < 4; ++ks) {
      s16x8 af[4], bfr[4];
      #pragma unroll
      for (int i = 0; i < 4; ++i) {
        int row = wm * 64 + i * 16 + lr;
        af[i] = *(const s16x8*)&sA[row * LD + swz_chunk(row, ks * 4 + lg) * 8];
      }
      #pragma unroll
      for (int i = 0; i < 4; ++i) {
        int row = wn * 64 + i * 16 + lr;
        bfr[i] = *(const s16x8*)&sB[row * LD + swz_chunk(row, ks * 4 + lg) * 8];
      }
      #pragma unroll
      for (int i = 0; i < 4; ++i)
        #pragma unroll
        for (int j = 0; j < 4; ++j)
          acc[i][j] = mfma16(af[i], bfr[j], acc[i][j]);
    }
  }
  float* out = mo + (size_t)b * YQ * DQ;
  int rb = wm * 64 + lg * 4;
  int cb_ = wn * 64 + lr;
  #pragma unroll
  for (int i = 0; i < 4; ++i)
    #pragma unroll
    for (int j = 0; j < 4; ++j) {
      int col = d0 + cb_ + j * 16;
      #pragma unroll
      for (int q = 0; q < 4; ++q) {
        int r = y0 + rb + i * 16 + q;
        if (r < YQ) out[(size_t)r * DQ + col] = acc[i][j][q];
      }
    }
}

// ------- y = m . final_w + b ; per-block loss partial (NO hot atomics) ------
__global__ void k_final(const float* __restrict__ m_in, const float* __restrict__ fw,
                        const float* __restrict__ fb, const float* __restrict__ tgt,
                        float* __restrict__ yo, float* __restrict__ part) {
  int y = blockIdx.x;
  int lane = threadIdx.x & 63;
  int b = threadIdx.x >> 6;      // 4 waves = 4 batches
  const float* mp = m_in + ((size_t)b * YQ + y) * DQ;
  const float* wp = fw + (size_t)y * DQ;
  float s = 0.f;
  #pragma unroll
  for (int i = 0; i < 8; ++i) {
    int e = lane + i * 64;
    s += mp[e] * wp[e];
  }
  #pragma unroll
  for (int o = 32; o > 0; o >>= 1) s += __shfl_xor(s, o);
  __shared__ float pl[4];
  if (lane == 0) {
    float yv = s + fb[y];
    yo[(size_t)b * YQ + y] = yv;
    float t = tgt[(size_t)b * YQ + y];
    pl[b] = fmaxf(yv, 0.f) - yv * t + log1pf(__expf(-fabsf(yv)));
  }
  __syncthreads();
  if (threadIdx.x == 0)
    part[y] = (pl[0] + pl[1]) + (pl[2] + pl[3]);
}

// ------- reduce 8922 per-label partials -> mean loss ------------------------
__global__ void k_loss_fin(const float* __restrict__ part, float* __restrict__ out) {
  int tid = threadIdx.x;
  float s = 0.f;
  for (int i = tid; i < YQ; i += 256) s += part[i];
  #pragma unroll
  for (int o = 32; o > 0; o >>= 1) s += __shfl_xor(s, o);
  __shared__ float red[4];
  int lane = tid & 63, wave = tid >> 6;
  if (lane == 0) red[wave] = s;
  __syncthreads();
  if (tid == 0)
    out[0] = ((red[0] + red[1]) + (red[2] + red[3])) * (1.0f / (float)(BQ * YQ));
}

extern "C" void kernel_launch(void* const* d_in, const int* in_sizes, int n_in,
                              void* d_out, int out_size, void* d_ws, size_t ws_size,
                              hipStream_t stream) {
  const float* x      = (const float*)d_in[0];
  const float* target = (const float*)d_in[1];
  const int*   c2t    = (const int*)d_in[2];
  const float* embed  = (const float*)d_in[3];
  const float* cw     = (const float*)d_in[4];
  const float* cb     = (const float*)d_in[5];
  const float* fw     = (const float*)d_in[6];
  const float* fb     = (const float*)d_in[7];

  char* ws = (char*)d_ws;
  ushort* xb   = (ushort*)(ws);                 //  8,388,608 B
  ushort* xT   = (ushort*)(ws + 8388608);       //  8,388,608 B
  ushort* Wp   = (ushort*)(ws + 16777216);      //  1,179,648 B
  ushort* U    = (ushort*)(ws + 17956864);      //  9,175,040 B (YPAD x D bf16)
  float* lpart = (float*)(ws + 27131904);       //  35,688 B (per-label loss)
  float* part  = (float*)(ws + 27167744);       //  9,136,128 B (sm partials)
  float* rst   = (float*)(ws + 36303872);       //  285,504 B (rowstats M,1/Z)
  const size_t SWS_OFF = 36589568;              // (64B aligned)
  const size_t SWS_BYTES = (size_t)BQ * YQ * SQ * 4;      // 292,552,704
  const size_t NEED_A = SWS_OFF + SWS_BYTES;              // ~329 MB
  const size_t ABF_OFF = SWS_OFF;
  const size_t NEED_B1 = ABF_OFF + (size_t)BQ * YQ * SQ * 2;  // ~183 MB
  bool mode_a = (ws_size >= NEED_A);
  bool use_abf = (!mode_a) && (ws_size >= NEED_B1);
  float* Sws = (float*)(ws + SWS_OFF);
  ushort* abf = use_abf ? (ushort*)(ws + ABF_OFF) : (ushort*)0;

  float* out       = (float*)d_out;
  float* out_y     = out;                               // [B][Y]
  float* out_loss  = out + (size_t)BQ * YQ;             // scalar
  float* out_alpha = out + (size_t)BQ * YQ + 1;         // [B][Y][S]
  float* out_m     = out_alpha + (size_t)BQ * YQ * SQ;  // [B][Y][D]

  hipMemsetAsync(U, 0, (size_t)YPAD * DQ * 2, stream);

  k_prep_x<<<dim3(SQ / 32, DQ / 32, BQ), dim3(32, 32), 0, stream>>>(x, xb, xT);
  k_pack_w<<<dim3((KQ * DQ * EP + 255) / 256), 256, 0, stream>>>(cw, Wp);
  k_conv<<<dim3(4, (YQ + 3) / 4), 256, 0, stream>>>(c2t, embed, Wp, cb, U);

  float* Sdst = mode_a ? Sws : out_alpha;
  k_scores<<<dim3(SQ / 128, (YQ + 127) / 128, BQ), 256, 0, stream>>>(U, xb, Sdst, part);
  k_smfix<<<dim3((BQ * YQ + 255) / 256), 256, 0, stream>>>(part, rst);

  if (mode_a) {
    k_pv_f<<<dim3(DQ / 128, (YQ + 127) / 128, BQ), 256, 0, stream>>>(
        Sws, rst, xT, out_m, out_alpha);
  } else {
    k_alpha<<<dim3(BQ * YQ), 256, 0, stream>>>(out_alpha, rst, abf);
    if (use_abf)
      k_pv<true><<<dim3(DQ / 128, (YQ + 127) / 128, BQ), 256, 0, stream>>>(
          out_alpha, abf, xT, out_m);
    else
      k_pv<false><<<dim3(DQ / 128, (YQ + 127) / 128, BQ), 256, 0, stream>>>(
          out_alpha, abf, xT, out_m);
  }
  k_final<<<dim3(YQ), 256, 0, stream>>>(out_m, fw, fb, target, out_y, lpart);
  k_loss_fin<<<1, 256, 0, stream>>>(lpart, out_loss);
}

// Round 6
// 986.374 us; speedup vs baseline: 1.1313x; 1.1313x over previous
//
#include <hip/hip_runtime.h>
#include <math.h>

#define BQ 4
#define SQ 2048
#define DQ 512
#define YQ 8922
#define TQ 32
#define EQ 100
#define EP 128      // E padded for MFMA K-steps
#define KQ 9
#define LD 128      // conv/scores LDS leading dim (bf16) = 256B rows, 4-bit XOR
#define TP 40       // padded t-rows per label (4 halo each side)
#define YPAD 8960

typedef float f32x4 __attribute__((ext_vector_type(4)));
typedef short s16x8 __attribute__((ext_vector_type(8)));

static __device__ __forceinline__ f32x4 mfma16(s16x8 a, s16x8 b, f32x4 c) {
  return __builtin_amdgcn_mfma_f32_16x16x32_bf16(a, b, c, 0, 0, 0);
}

static __device__ __forceinline__ ushort f2bf(float f) {
  union { float f; unsigned u; } v; v.f = f;
  unsigned r = (v.u + 0x7FFFu + ((v.u >> 16) & 1u)) >> 16;
  return (ushort)r;
}

static __device__ __forceinline__ f32x4 ld4u(const float* p) {
  f32x4 v; __builtin_memcpy(&v, p, 16); return v;
}

// 4-bit XOR swizzle for 128-elem (256B) rows: 16 chunks (R3-proven)
static __device__ __forceinline__ int swz_chunk(int row, int chunk) {
  return chunk ^ (row & 15);
}
// 3-bit XOR swizzle for 64-elem (128B) rows: 8 chunks, 2-way max (free)
static __device__ __forceinline__ int swz3(int row, int chunk) {
  return chunk ^ (row & 7);
}

// ---------------- prep: x -> bf16 [B][S][D] and transposed bf16 [B][D][S] ----
__global__ void k_prep_x(const float* __restrict__ x, ushort* __restrict__ xb,
                         ushort* __restrict__ xT) {
  __shared__ ushort sm[32][33];
  int b = blockIdx.z;
  int s0 = blockIdx.x * 32;
  int d0 = blockIdx.y * 32;
  int tx = threadIdx.x, ty = threadIdx.y;
  float v = x[((size_t)b * SQ + s0 + ty) * DQ + d0 + tx];
  ushort h = f2bf(v);
  xb[((size_t)b * SQ + s0 + ty) * DQ + d0 + tx] = h;
  sm[ty][tx] = h;
  __syncthreads();
  xT[((size_t)b * DQ + d0 + ty) * SQ + s0 + tx] = sm[tx][ty];
}

// ---------------- pack conv_w [D][E][K] -> Wp bf16 [K][D][EP] (e>=100 -> 0) --
__global__ void k_pack_w(const float* __restrict__ cw, ushort* __restrict__ Wp) {
  int i = blockIdx.x * 256 + threadIdx.x;
  if (i >= KQ * DQ * EP) return;
  int e = i & (EP - 1);
  int d = (i >> 7) & (DQ - 1);
  int kk = i >> 16;
  float v = (e < EQ) ? cw[((size_t)d * EQ + e) * KQ + kk] : 0.f;
  Wp[i] = f2bf(v);
}

// ---------------- conv + maxpool + tanh + scale -> U bf16 [YQ][D] -----------
__launch_bounds__(256, 2)
__global__ void k_conv(const int* __restrict__ c2t, const float* __restrict__ embed,
                       const ushort* __restrict__ Wp, const float* __restrict__ cb,
                       ushort* __restrict__ U) {
  __shared__ ushort sA[4 * TP * LD];   // 40 KB: 4 labels x 40 t (4-halo) x 128 e
  __shared__ ushort sB[128 * LD];      // 32 KB: 128 d x 128 e (one kk)
  const f32x4 fz4 = {0.f, 0.f, 0.f, 0.f};
  int tid = threadIdx.x;
  int d0 = blockIdx.x * 128;
  int y0 = blockIdx.y * 4;
  int lane = tid & 63, wave = tid >> 6;
  int wm = wave & 1, wn = wave >> 1;
  int lr = lane & 15, lg = lane >> 4;

  // stage title embeddings with zero halo: rows = yl*40 + (ts+4), ts in [-4,36)
  #pragma unroll
  for (int it = 0; it < 2; ++it) {
    int u = tid + it * 256;
    if (u < 2 * 4 * TP) {
      int row = u >> 1, half = u & 1;
      int yl = row / TP, tt = row - yl * TP;
      int ts = tt - 4;
      int y = y0 + yl;
      const float* src = 0;
      if (y < YQ && (unsigned)ts < (unsigned)TQ)
        src = embed + (size_t)c2t[y * TQ + ts] * EQ + half * 64;
      #pragma unroll
      for (int j = 0; j < 16; ++j) {
        int col = half * 64 + j * 4;
        f32x4 v = fz4;
        if (src != 0 && col + 4 <= EQ) v = *(const f32x4*)(src + j * 4);
        ushort4 h = make_ushort4(f2bf(v.x), f2bf(v.y), f2bf(v.z), f2bf(v.w));
        int pc = swz_chunk(row, col >> 3);
        *(ushort4*)&sA[row * LD + pc * 8 + (col & 7)] = h;
      }
    }
  }

  // B prologue: kk=0 via registers
  s16x8 breg[8];
  {
    const ushort* src = Wp + (size_t)d0 * EP;
    #pragma unroll
    for (int it = 0; it < 8; ++it) {
      int gi = tid + it * 256, r = gi >> 4, g = gi & 15;
      breg[it] = *(const s16x8*)(src + (size_t)r * EP + g * 8);
    }
    #pragma unroll
    for (int it = 0; it < 8; ++it) {
      int gi = tid + it * 256, r = gi >> 4, g = gi & 15;
      *(s16x8*)&sB[r * LD + swz_chunk(r, g) * 8] = breg[it];
    }
  }
  __syncthreads();

  f32x4 acc[4][4];
  #pragma unroll
  for (int i = 0; i < 4; ++i)
    #pragma unroll
    for (int j = 0; j < 4; ++j) acc[i][j] = fz4;

  for (int kk = 0; kk < KQ; ++kk) {
    // T14: issue next-kk weight loads into regs BEFORE compute
    if (kk + 1 < KQ) {
      const ushort* src = Wp + ((size_t)(kk + 1) * DQ + d0) * EP;
      #pragma unroll
      for (int it = 0; it < 8; ++it) {
        int gi = tid + it * 256, r = gi >> 4, g = gi & 15;
        breg[it] = *(const s16x8*)(src + (size_t)r * EP + g * 8);
      }
    }
    #pragma unroll
    for (int ee = 0; ee < 4; ++ee) {
      s16x8 af[4], bfr[4];
      #pragma unroll
      for (int i = 0; i < 4; ++i) {
        int rowm = wm * 64 + i * 16 + lr;
        int yl = rowm >> 5;
        int row = yl * TP + (rowm & 31) + kk;   // halo-padded, unconditional
        af[i] = *(const s16x8*)&sA[row * LD + swz_chunk(row, ee * 4 + lg) * 8];
      }
      #pragma unroll
      for (int i = 0; i < 4; ++i) {
        int row = wn * 64 + i * 16 + lr;
        bfr[i] = *(const s16x8*)&sB[row * LD + swz_chunk(row, ee * 4 + lg) * 8];
      }
      __builtin_amdgcn_s_setprio(1);
      #pragma unroll
      for (int i = 0; i < 4; ++i)
        #pragma unroll
        for (int j = 0; j < 4; ++j)
          acc[i][j] = mfma16(af[i], bfr[j], acc[i][j]);
      __builtin_amdgcn_s_setprio(0);
    }
    __syncthreads();
    if (kk + 1 < KQ) {
      #pragma unroll
      for (int it = 0; it < 8; ++it) {
        int gi = tid + it * 256, r = gi >> 4, g = gi & 15;
        *(s16x8*)&sB[r * LD + swz_chunk(r, g) * 8] = breg[it];
      }
      __syncthreads();
    }
  }

  // in-register epilogue: maxpool over t via in-lane fmax + shfl, tanh, scale
  const float scl = 0.04419417382415922f;   // 1/sqrt(D)
  #pragma unroll
  for (int L2 = 0; L2 < 2; ++L2) {
    int y = y0 + wm * 2 + L2;
    #pragma unroll
    for (int j = 0; j < 4; ++j) {
      float mx = -3.0e38f;
      #pragma unroll
      for (int ii = 0; ii < 2; ++ii)
        #pragma unroll
        for (int q = 0; q < 4; ++q)
          mx = fmaxf(mx, acc[L2 * 2 + ii][j][q]);
      mx = fmaxf(mx, __shfl_xor(mx, 16));
      mx = fmaxf(mx, __shfl_xor(mx, 32));
      if (lane < 16 && y < YQ) {
        int col = d0 + wn * 64 + j * 16 + lane;
        U[(size_t)y * DQ + col] = f2bf(tanhf(mx + cb[col]) * scl);
      }
    }
  }
}

// ---- scores = U . xb^T -> raw S + per-(row,64col) {max,sumexp} partials ----
__launch_bounds__(256, 2)
__global__ void k_scores(const ushort* __restrict__ U, const ushort* __restrict__ xb,
                         float* __restrict__ sc, float* __restrict__ part) {
  __shared__ ushort sA[128 * LD];
  __shared__ ushort sB[128 * LD];
  const f32x4 fz4 = {0.f, 0.f, 0.f, 0.f};
  int tid = threadIdx.x;
  int s0 = blockIdx.x * 128;
  int y0 = blockIdx.y * 128;
  int b = blockIdx.z;
  const ushort* Ap = U + (size_t)y0 * DQ;
  const ushort* Bp = xb + ((size_t)b * SQ + s0) * DQ;
  f32x4 acc[4][4];
  #pragma unroll
  for (int i = 0; i < 4; ++i)
    #pragma unroll
    for (int j = 0; j < 4; ++j) acc[i][j] = fz4;
  int lane = tid & 63, wave = tid >> 6;
  int wm = wave & 1, wn = wave >> 1;
  int lr = lane & 15, lg = lane >> 4;

  for (int kc = 0; kc < DQ; kc += 128) {
    __syncthreads();
    #pragma unroll
    for (int it = 0; it < 8; ++it) {
      int gi = tid + it * 256;
      int r = gi >> 4, g = gi & 15;
      int pofs = r * LD + swz_chunk(r, g) * 8;
      *(s16x8*)&sA[pofs] = *(const s16x8*)(Ap + (size_t)r * DQ + kc + g * 8);
      *(s16x8*)&sB[pofs] = *(const s16x8*)(Bp + (size_t)r * DQ + kc + g * 8);
    }
    __syncthreads();
    #pragma unroll
    for (int ks = 0; ks < 4; ++ks) {
      s16x8 af[4], bfr[4];
      #pragma unroll
      for (int i = 0; i < 4; ++i) {
        int row = wm * 64 + i * 16 + lr;
        af[i] = *(const s16x8*)&sA[row * LD + swz_chunk(row, ks * 4 + lg) * 8];
      }
      #pragma unroll
      for (int i = 0; i < 4; ++i) {
        int row = wn * 64 + i * 16 + lr;
        bfr[i] = *(const s16x8*)&sB[row * LD + swz_chunk(row, ks * 4 + lg) * 8];
      }
      #pragma unroll
      for (int i = 0; i < 4; ++i)
        #pragma unroll
        for (int j = 0; j < 4; ++j)
          acc[i][j] = mfma16(af[i], bfr[j], acc[i][j]);
    }
  }
  float* out = sc + (size_t)b * YQ * SQ;
  int rb = wm * 64 + lg * 4;
  int cb_ = wn * 64 + lr;
  #pragma unroll
  for (int i = 0; i < 4; ++i)
    #pragma unroll
    for (int j = 0; j < 4; ++j) {
      int col = s0 + cb_ + j * 16;
      #pragma unroll
      for (int q = 0; q < 4; ++q) {
        int r = y0 + rb + i * 16 + q;
        if (r < YQ) out[(size_t)r * SQ + col] = acc[i][j][q];
      }
    }

  int hb = blockIdx.x * 2 + wn;   // 64-col block index in [0,32)
  #pragma unroll
  for (int i = 0; i < 4; ++i)
    #pragma unroll
    for (int q = 0; q < 4; ++q) {
      float mx = fmaxf(fmaxf(acc[i][0][q], acc[i][1][q]),
                       fmaxf(acc[i][2][q], acc[i][3][q]));
      #pragma unroll
      for (int o = 1; o < 16; o <<= 1) mx = fmaxf(mx, __shfl_xor(mx, o));
      float se = 0.f;
      #pragma unroll
      for (int j = 0; j < 4; ++j) se += __expf(acc[i][j][q] - mx);
      #pragma unroll
      for (int o = 1; o < 16; o <<= 1) se += __shfl_xor(se, o);
      int r = y0 + rb + i * 16 + q;
      if (lr == 0 && r < YQ) {
        float* pp = part + ((size_t)(b * YQ + r) * 32 + hb) * 2;
        pp[0] = mx;
        pp[1] = se;
      }
    }
}

// ---- merge 32 per-row partials -> rowstats {M, 1/Z} ------------------------
__global__ void k_smfix(const float* __restrict__ part, float* __restrict__ rs) {
  int t = blockIdx.x * 256 + threadIdx.x;
  if (t >= BQ * YQ) return;
  const float* pp = part + (size_t)t * 64;
  float M = -3.0e38f;
  #pragma unroll
  for (int h = 0; h < 32; ++h) M = fmaxf(M, pp[h * 2]);
  float Z = 0.f;
  #pragma unroll
  for (int h = 0; h < 32; ++h) Z += __expf(pp[h * 2] - M) * pp[h * 2 + 1];
  rs[t * 2] = M;
  rs[t * 2 + 1] = 1.0f / Z;
}

// ---- in-place S -> alpha (f32) + bf16 copy ---------------------------------
__global__ void k_alpha(float* __restrict__ a, const float* __restrict__ rs,
                        ushort* __restrict__ abf) {
  int r = blockIdx.x;              // b*YQ + y
  float M = rs[r * 2], iZ = rs[r * 2 + 1];
  float* p = a + (size_t)r * SQ;
  ushort* q = abf ? abf + (size_t)r * SQ : 0;
  int tid = threadIdx.x;
  #pragma unroll
  for (int i = 0; i < 8; ++i) {
    int e = tid + i * 256;
    float v = __expf(p[e] - M) * iZ;
    p[e] = v;
    if (q) q[e] = f2bf(v);
  }
}

// ---- PV v2: m = alpha . x ; 128y x 256d tile, 8 waves, K-chunk 64 ----------
__launch_bounds__(512, 4)
__global__ void k_pv2(const ushort* __restrict__ abf, const ushort* __restrict__ xT,
                      float* __restrict__ mo) {
  __shared__ ushort sA[128 * 64];   // 16 KB: 128 y-rows x 64 s
  __shared__ ushort sB[256 * 64];   // 32 KB: 256 d-rows x 64 s
  const f32x4 fz4 = {0.f, 0.f, 0.f, 0.f};
  const s16x8 sz8 = {0, 0, 0, 0, 0, 0, 0, 0};
  int tid = threadIdx.x;
  int d0 = blockIdx.x * 256;
  int y0 = blockIdx.y * 128;
  int b = blockIdx.z;
  int lane = tid & 63, wave = tid >> 6;
  int wm = wave >> 1;       // 0..3 : 32-row group
  int wn = wave & 1;        // 0..1 : 128-col group
  int lr = lane & 15, lg = lane >> 4;

  const ushort* Ap = abf + ((size_t)b * YQ + y0) * SQ;
  const ushort* Bp = xT + ((size_t)b * DQ + d0) * SQ;

  f32x4 acc[2][8];
  #pragma unroll
  for (int i = 0; i < 2; ++i)
    #pragma unroll
    for (int j = 0; j < 8; ++j) acc[i][j] = fz4;

  for (int kc = 0; kc < SQ; kc += 64) {
    // stage A: 128 rows x 8 chunks = 1024 units
    #pragma unroll
    for (int p = 0; p < 2; ++p) {
      int u = tid + p * 512;
      int r = u >> 3, c = u & 7;
      int y = y0 + r;
      s16x8 v = sz8;
      if (y < YQ) v = *(const s16x8*)(Ap + (size_t)r * SQ + kc + c * 8);
      *(s16x8*)&sA[r * 64 + swz3(r, c) * 8] = v;
    }
    // stage B: 256 rows x 8 chunks = 2048 units
    #pragma unroll
    for (int p = 0; p < 4; ++p) {
      int u = tid + p * 512;
      int r = u >> 3, c = u & 7;
      *(s16x8*)&sB[r * 64 + swz3(r, c) * 8] =
          *(const s16x8*)(Bp + (size_t)r * SQ + kc + c * 8);
    }
    __syncthreads();
    #pragma unroll
    for (int ks = 0; ks < 2; ++ks) {
      s16x8 af[2];
      #pragma unroll
      for (int i = 0; i < 2; ++i) {
        int row = wm * 32 + i * 16 + lr;
        af[i] = *(const s16x8*)&sA[row * 64 + swz3(row, ks * 4 + lg) * 8];
      }
      __builtin_amdgcn_s_setprio(1);
      #pragma unroll
      for (int j = 0; j < 8; ++j) {
        int row = wn * 128 + j * 16 + lr;
        s16x8 bf = *(const s16x8*)&sB[row * 64 + swz3(row, ks * 4 + lg) * 8];
        acc[0][j] = mfma16(af[0], bf, acc[0][j]);
        acc[1][j] = mfma16(af[1], bf, acc[1][j]);
      }
      __builtin_amdgcn_s_setprio(0);
    }
    __syncthreads();
  }

  float* out = mo + (size_t)b * YQ * DQ;
  #pragma unroll
  for (int i = 0; i < 2; ++i)
    #pragma unroll
    for (int q = 0; q < 4; ++q) {
      int r = y0 + wm * 32 + i * 16 + lg * 4 + q;
      if (r >= YQ) continue;
      #pragma unroll
      for (int j = 0; j < 8; ++j) {
        int col = d0 + wn * 128 + j * 16 + lr;
        out[(size_t)r * DQ + col] = acc[i][j][q];
      }
    }
}

// ---- PV fallback (small ws): m = alpha(f32,d_out) . x ----------------------
__launch_bounds__(256, 2)
__global__ void k_pv(const float* __restrict__ alpha, const ushort* __restrict__ xT,
                     float* __restrict__ mo) {
  __shared__ ushort sA[128 * LD];
  __shared__ ushort sB[128 * LD];
  const f32x4 fz4 = {0.f, 0.f, 0.f, 0.f};
  int tid = threadIdx.x;
  int d0 = blockIdx.x * 128;
  int y0 = blockIdx.y * 128;
  int b = blockIdx.z;
  const float* Ap = alpha + ((size_t)b * YQ + y0) * SQ;
  const ushort* Bp = xT + ((size_t)b * DQ + d0) * SQ;
  f32x4 acc[4][4];
  #pragma unroll
  for (int i = 0; i < 4; ++i)
    #pragma unroll
    for (int j = 0; j < 4; ++j) acc[i][j] = fz4;
  int lane = tid & 63, wave = tid >> 6;
  int wm = wave & 1, wn = wave >> 1;
  int lr = lane & 15, lg = lane >> 4;

  for (int kc = 0; kc < SQ; kc += 128) {
    __syncthreads();
    #pragma unroll
    for (int it = 0; it < 8; ++it) {
      int gi = tid + it * 256;
      int r = gi >> 4, g = gi & 15;
      int y = y0 + r;
      int pofs = r * LD + swz_chunk(r, g) * 8;
      ushort4 h0 = make_ushort4(0, 0, 0, 0), h1 = make_ushort4(0, 0, 0, 0);
      if (y < YQ) {
        f32x4 v0 = ld4u(Ap + (size_t)r * SQ + kc + g * 8);
        f32x4 v1 = ld4u(Ap + (size_t)r * SQ + kc + g * 8 + 4);
        h0 = make_ushort4(f2bf(v0.x), f2bf(v0.y), f2bf(v0.z), f2bf(v0.w));
        h1 = make_ushort4(f2bf(v1.x), f2bf(v1.y), f2bf(v1.z), f2bf(v1.w));
      }
      *(ushort4*)&sA[pofs] = h0;
      *(ushort4*)&sA[pofs + 4] = h1;
      *(s16x8*)&sB[pofs] = *(const s16x8*)(Bp + (size_t)r * SQ + kc + g * 8);
    }
    __syncthreads();
    #pragma unroll
    for (int ks = 0; ks < 4; ++ks) {
      s16x8 af[4], bfr[4];
      #pragma unroll
      for (int i = 0; i < 4; ++i) {
        int row = wm * 64 + i * 16 + lr;
        af[i] = *(const s16x8*)&sA[row * LD + swz_chunk(row, ks * 4 + lg) * 8];
      }
      #pragma unroll
      for (int i = 0; i < 4; ++i) {
        int row = wn * 64 + i * 16 + lr;
        bfr[i] = *(const s16x8*)&sB[row * LD + swz_chunk(row, ks * 4 + lg) * 8];
      }
      #pragma unroll
      for (int i = 0; i < 4; ++i)
        #pragma unroll
        for (int j = 0; j < 4; ++j)
          acc[i][j] = mfma16(af[i], bfr[j], acc[i][j]);
    }
  }
  float* out = mo + (size_t)b * YQ * DQ;
  int rb = wm * 64 + lg * 4;
  int cb_ = wn * 64 + lr;
  #pragma unroll
  for (int i = 0; i < 4; ++i)
    #pragma unroll
    for (int j = 0; j < 4; ++j) {
      int col = d0 + cb_ + j * 16;
      #pragma unroll
      for (int q = 0; q < 4; ++q) {
        int r = y0 + rb + i * 16 + q;
        if (r < YQ) out[(size_t)r * DQ + col] = acc[i][j][q];
      }
    }
}

// ------- y = m . final_w + b ; per-block loss partial (NO hot atomics) ------
__global__ void k_final(const float* __restrict__ m_in, const float* __restrict__ fw,
                        const float* __restrict__ fb, const float* __restrict__ tgt,
                        float* __restrict__ yo, float* __restrict__ part) {
  int y = blockIdx.x;
  int lane = threadIdx.x & 63;
  int b = threadIdx.x >> 6;      // 4 waves = 4 batches
  const float* mp = m_in + ((size_t)b * YQ + y) * DQ;
  const float* wp = fw + (size_t)y * DQ;
  float s = 0.f;
  #pragma unroll
  for (int i = 0; i < 8; ++i) {
    int e = lane + i * 64;
    s += mp[e] * wp[e];
  }
  #pragma unroll
  for (int o = 32; o > 0; o >>= 1) s += __shfl_xor(s, o);
  __shared__ float pl[4];
  if (lane == 0) {
    float yv = s + fb[y];
    yo[(size_t)b * YQ + y] = yv;
    float t = tgt[(size_t)b * YQ + y];
    pl[b] = fmaxf(yv, 0.f) - yv * t + log1pf(__expf(-fabsf(yv)));
  }
  __syncthreads();
  if (threadIdx.x == 0)
    part[y] = (pl[0] + pl[1]) + (pl[2] + pl[3]);
}

// ------- reduce 8922 per-label partials -> mean loss ------------------------
__global__ void k_loss_fin(const float* __restrict__ part, float* __restrict__ out) {
  int tid = threadIdx.x;
  float s = 0.f;
  for (int i = tid; i < YQ; i += 256) s += part[i];
  #pragma unroll
  for (int o = 32; o > 0; o >>= 1) s += __shfl_xor(s, o);
  __shared__ float red[4];
  int lane = tid & 63, wave = tid >> 6;
  if (lane == 0) red[wave] = s;
  __syncthreads();
  if (tid == 0)
    out[0] = ((red[0] + red[1]) + (red[2] + red[3])) * (1.0f / (float)(BQ * YQ));
}

extern "C" void kernel_launch(void* const* d_in, const int* in_sizes, int n_in,
                              void* d_out, int out_size, void* d_ws, size_t ws_size,
                              hipStream_t stream) {
  const float* x      = (const float*)d_in[0];
  const float* target = (const float*)d_in[1];
  const int*   c2t    = (const int*)d_in[2];
  const float* embed  = (const float*)d_in[3];
  const float* cw     = (const float*)d_in[4];
  const float* cb     = (const float*)d_in[5];
  const float* fw     = (const float*)d_in[6];
  const float* fb     = (const float*)d_in[7];

  char* ws = (char*)d_ws;
  ushort* xb   = (ushort*)(ws);                 //  8,388,608 B
  ushort* xT   = (ushort*)(ws + 8388608);       //  8,388,608 B
  ushort* Wp   = (ushort*)(ws + 16777216);      //  1,179,648 B
  ushort* U    = (ushort*)(ws + 17956864);      //  9,175,040 B
  float* lpart = (float*)(ws + 27131904);       //  35,688 B
  float* part  = (float*)(ws + 27167744);       //  9,136,128 B (sm partials)
  float* rst   = (float*)(ws + 36303872);       //  285,504 B (rowstats M,1/Z)
  const size_t ABF_OFF = 36589568;
  const size_t NEED_ABF = ABF_OFF + (size_t)BQ * YQ * SQ * 2;   // ~183 MB
  bool use_abf = (ws_size >= NEED_ABF);
  ushort* abf = use_abf ? (ushort*)(ws + ABF_OFF) : (ushort*)0;

  float* out       = (float*)d_out;
  float* out_y     = out;                               // [B][Y]
  float* out_loss  = out + (size_t)BQ * YQ;             // scalar
  float* out_alpha = out + (size_t)BQ * YQ + 1;         // [B][Y][S]
  float* out_m     = out_alpha + (size_t)BQ * YQ * SQ;  // [B][Y][D]

  hipMemsetAsync(U, 0, (size_t)YPAD * DQ * 2, stream);

  k_prep_x<<<dim3(SQ / 32, DQ / 32, BQ), dim3(32, 32), 0, stream>>>(x, xb, xT);
  k_pack_w<<<dim3((KQ * DQ * EP + 255) / 256), 256, 0, stream>>>(cw, Wp);
  k_conv<<<dim3(4, (YQ + 3) / 4), 256, 0, stream>>>(c2t, embed, Wp, cb, U);
  k_scores<<<dim3(SQ / 128, (YQ + 127) / 128, BQ), 256, 0, stream>>>(U, xb, out_alpha, part);
  k_smfix<<<dim3((BQ * YQ + 255) / 256), 256, 0, stream>>>(part, rst);
  k_alpha<<<dim3(BQ * YQ), 256, 0, stream>>>(out_alpha, rst, abf);
  if (use_abf)
    k_pv2<<<dim3(DQ / 256, (YQ + 127) / 128, BQ), 512, 0, stream>>>(abf, xT, out_m);
  else
    k_pv<<<dim3(DQ / 128, (YQ + 127) / 128, BQ), 256, 0, stream>>>(out_alpha, xT, out_m);
  k_final<<<dim3(YQ), 256, 0, stream>>>(out_m, fw, fb, target, out_y, lpart);
  k_loss_fin<<<1, 256, 0, stream>>>(lpart, out_loss);
}